// Round 9
// baseline (186.796 us; speedup 1.0000x reference)
//
#include <hip/hip_runtime.h>

typedef unsigned short ushort_t;
typedef __attribute__((ext_vector_type(8))) __bf16 bf16x8;
typedef __attribute__((ext_vector_type(4))) float f32x4;
typedef __attribute__((ext_vector_type(16))) float f32x16;
typedef __attribute__((ext_vector_type(4))) unsigned short us4;
typedef __attribute__((ext_vector_type(8))) unsigned short us8;
typedef __attribute__((ext_vector_type(4))) unsigned int u32x4;

#define AS1 __attribute__((address_space(1)))
#define AS3 __attribute__((address_space(3)))

__device__ __forceinline__ unsigned short f2bf(float f) {
    unsigned u = __float_as_uint(f);
    u += 0x7fff + ((u >> 16) & 1);   // RNE
    return (unsigned short)(u >> 16);
}

__device__ __forceinline__ unsigned cvtpk_bf16(float lo, float hi) {
    unsigned r;
    asm("v_cvt_pk_bf16_f32 %0, %1, %2" : "=v"(r) : "v"(lo), "v"(hi));
    return r;
}

__device__ __forceinline__ float fast_exp2(float x) {
    float r;
    asm("v_exp_f32 %0, %1" : "=v"(r) : "v"(x));
    return r;
}

// ---------------------------------------------------------------- convert x
__global__ void k_convert_x(const float* __restrict__ x, ushort_t* __restrict__ xb, int n4) {
    int i = blockIdx.x * blockDim.x + threadIdx.x;
    int stride = gridDim.x * blockDim.x;
    for (; i < n4; i += stride) {
        float4 f = reinterpret_cast<const float4*>(x)[i];
        us4 o = { f2bf(f.x), f2bf(f.y), f2bf(f.z), f2bf(f.w) };
        reinterpret_cast<us4*>(xb)[i] = o;
    }
}

// ------------------------------------------------- transpose weights -> bf16 [n][k]
__global__ void k_transpose_w(const float* __restrict__ wq, const float* __restrict__ wk,
                              const float* __restrict__ wv, const float* __restrict__ wo,
                              ushort_t* __restrict__ wqkvt, ushort_t* __restrict__ wot) {
    __shared__ float t[64][65];
    int bx = blockIdx.x;
    int w = bx >> 8;            // 0..3 : WQ WK WV WO
    int ti = bx & 255;
    int k0 = (ti >> 4) * 64, n0 = (ti & 15) * 64;
    const float* src = (w == 0) ? wq : (w == 1) ? wk : (w == 2) ? wv : wo;
    ushort_t* dst = (w < 3) ? (wqkvt + (size_t)w * 1048576) : wot;
    for (int i = threadIdx.x; i < 4096; i += 256) {
        int r = i >> 6, c = i & 63;
        t[c][r] = src[(size_t)(k0 + r) * 1024 + n0 + c];
    }
    __syncthreads();
    for (int i = threadIdx.x; i < 4096; i += 256) {
        int r = i >> 6, c = i & 63;
        dst[(size_t)(n0 + r) * 1024 + k0 + c] = f2bf(t[r][c]);
    }
}

// ---------------------------------------------------------------- QKV GEMM, 256x192 tile, pipelined phases
// (proven round 6/7: 0 bank conflicts, counted vmcnt, 4 barriers/tile)
__global__ __launch_bounds__(512, 2) void k_gemm_qkv256(
    const ushort_t* __restrict__ A, const ushort_t* __restrict__ Bm,
    ushort_t* __restrict__ qd, ushort_t* __restrict__ kd, ushort_t* __restrict__ vd) {
    __shared__ __attribute__((aligned(16))) ushort_t lds[2 * 28672];   // 112 KiB

    const int tid = threadIdx.x, wid = tid >> 6, lane = tid & 63;
    const int lr = lane & 15, lg = lane >> 4;
    const int wm = wid >> 2, wn = wid & 3;

    int bid = blockIdx.x;                       // 512 = 64 per XCD
    int wg = (bid & 7) * 64 + (bid >> 3);       // bijective XCD swizzle
    const int by = wg >> 4, bx = wg & 15;
    const int row0 = by * 256, col0 = bx * 192;

    const int srcrow = lane >> 2;
    const int srccol = (((lane & 3) * 16) ^ ((lane >> 5) << 5)) >> 1;   // ushort units
    const ushort_t* aS = A  + (size_t)(row0 + srcrow) * 1024 + srccol;
    const ushort_t* bS = Bm + (size_t)(col0 + srcrow) * 1024 + srccol;
    const int rdoff = (lr * 64 + lg * 16) ^ ((lr >> 3) << 5);           // bytes

    const int s0 = (wid & 3) + ((wid >> 2) << 3);   // A sr set {0..3, 8..11}
    const int s1 = s0 + 4;                          // A sr set {4..7, 12..15}
    const int bmix_sr = 8 + (wid & 3);              // B sr 8..11
    const int bmix_sc = wid >> 2;

#define STG_A(kt, sr, sc) \
    __builtin_amdgcn_global_load_lds((const AS1 void*)(aS + (size_t)(sr) * 16384 + (kt) * 64 + (sc) * 32), \
        (AS3 void*)((AS3 char*)lds + ((kt) & 1) * 57344 + (sr) * 2048 + (sc) * 1024), 16, 0, 0)
#define STG_B(kt, sr, sc) \
    __builtin_amdgcn_global_load_lds((const AS1 void*)(bS + (size_t)(sr) * 16384 + (kt) * 64 + (sc) * 32), \
        (AS3 void*)((AS3 char*)lds + ((kt) & 1) * 57344 + 32768 + (sr) * 2048 + (sc) * 1024), 16, 0, 0)
#define GRP1(kt)  { STG_A(kt, s0, 0); STG_B(kt, wid, 0); }   // 2 loads
#define GRP2(kt)  { STG_A(kt, s1, 0); }                      // 1 load
#define GRP3(kt)  { STG_A(kt, s0, 1); STG_B(kt, wid, 1); }   // 2 loads
#define GTOP(kt)  { STG_A(kt, s1, 1); STG_B(kt, bmix_sr, bmix_sc); }  // 2 loads

    f32x4 acc[8][3] = {};

    // prologue: tile0 complete (7), tile1 in-loop groups (5)
    GRP1(0); GRP2(0); GRP3(0); GTOP(0);
    GRP1(1); GRP2(1); GRP3(1);

#pragma unroll 1
    for (int kt = 0; kt < 16; ++kt) {
        if (kt < 15) asm volatile("s_waitcnt vmcnt(5)" ::: "memory");
        else         asm volatile("s_waitcnt vmcnt(0)" ::: "memory");
        __builtin_amdgcn_s_barrier();                 // buffer kt valid for all waves
        if (kt < 15) GTOP(kt + 1);

        const char* bufA = (const char*)lds + (kt & 1) * 57344;
        const char* bufB = bufA + 32768;

        bf16x8 av0[4], av1[4], bv0[3], bv1[3];
        // reads for phase 0 (sc0, mh0) + B sc0
#pragma unroll
        for (int x = 0; x < 4; ++x)
            av0[x] = *reinterpret_cast<const bf16x8*>(bufA + (wm * 8 + x) * 2048 + rdoff);
#pragma unroll
        for (int x = 0; x < 3; ++x)
            bv0[x] = *reinterpret_cast<const bf16x8*>(bufB + (wn * 3 + x) * 2048 + rdoff);

        // ---- phase 0
#pragma unroll
        for (int x = 0; x < 4; ++x)
            av1[x] = *reinterpret_cast<const bf16x8*>(bufA + (wm * 8 + 4 + x) * 2048 + rdoff);
        __builtin_amdgcn_s_setprio(1);
#pragma unroll
        for (int mf = 0; mf < 4; ++mf)
#pragma unroll
            for (int nf = 0; nf < 3; ++nf)
                acc[mf][nf] = __builtin_amdgcn_mfma_f32_16x16x32_bf16(av0[mf], bv0[nf], acc[mf][nf], 0, 0, 0);
        __builtin_amdgcn_s_setprio(0);
        __builtin_amdgcn_s_barrier();

        // ---- phase 1
#pragma unroll
        for (int x = 0; x < 4; ++x)
            av0[x] = *reinterpret_cast<const bf16x8*>(bufA + (wm * 8 + x) * 2048 + 1024 + rdoff);
#pragma unroll
        for (int x = 0; x < 3; ++x)
            bv1[x] = *reinterpret_cast<const bf16x8*>(bufB + (wn * 3 + x) * 2048 + 1024 + rdoff);
        __builtin_amdgcn_s_setprio(1);
#pragma unroll
        for (int mf = 0; mf < 4; ++mf)
#pragma unroll
            for (int nf = 0; nf < 3; ++nf)
                acc[4 + mf][nf] = __builtin_amdgcn_mfma_f32_16x16x32_bf16(av1[mf], bv0[nf], acc[4 + mf][nf], 0, 0, 0);
        __builtin_amdgcn_s_setprio(0);
        if (kt < 14) GRP1(kt + 2);
        __builtin_amdgcn_s_barrier();

        // ---- phase 2
#pragma unroll
        for (int x = 0; x < 4; ++x)
            av1[x] = *reinterpret_cast<const bf16x8*>(bufA + (wm * 8 + 4 + x) * 2048 + 1024 + rdoff);
        __builtin_amdgcn_s_setprio(1);
#pragma unroll
        for (int mf = 0; mf < 4; ++mf)
#pragma unroll
            for (int nf = 0; nf < 3; ++nf)
                acc[mf][nf] = __builtin_amdgcn_mfma_f32_16x16x32_bf16(av0[mf], bv1[nf], acc[mf][nf], 0, 0, 0);
        __builtin_amdgcn_s_setprio(0);
        if (kt < 14) GRP2(kt + 2);
        __builtin_amdgcn_s_barrier();

        // ---- phase 3
        __builtin_amdgcn_s_setprio(1);
#pragma unroll
        for (int mf = 0; mf < 4; ++mf)
#pragma unroll
            for (int nf = 0; nf < 3; ++nf)
                acc[4 + mf][nf] = __builtin_amdgcn_mfma_f32_16x16x32_bf16(av1[mf], bv1[nf], acc[4 + mf][nf], 0, 0, 0);
        __builtin_amdgcn_s_setprio(0);
        if (kt < 14) GRP3(kt + 2);
    }
#undef STG_A
#undef STG_B
#undef GRP1
#undef GRP2
#undef GRP3
#undef GTOP

    // ---- epilogue: scatter to [B,H,T,Dh]; per-fragment Q/K/V select (tiles straddle)
#pragma unroll
    for (int mi = 0; mi < 8; ++mi) {
#pragma unroll
        for (int nf = 0; nf < 3; ++nf) {
            int col = col0 + wn * 48 + nf * 16 + lr;
            int w = col >> 10;
            int c1 = col & 1023;
            int h = c1 >> 6, dh = c1 & 63;
            ushort_t* dst = (w == 0) ? qd : (w == 1) ? kd : vd;
            const float osc = (w == 0) ? 0.18033688f : 1.0f;   // 0.125*log2(e) for Q
#pragma unroll
            for (int e = 0; e < 4; ++e) {
                int row = row0 + wm * 128 + mi * 16 + lg * 4 + e;
                int b = row >> 11, t = row & 2047;
                dst[(((size_t)(b * 16 + h)) * 2048 + t) * 64 + dh] = f2bf(acc[mi][nf][e] * osc);
            }
        }
    }
}

// ---------------------------------------------------------------- V transpose [bh][t][dh] -> [bh][dh][t]
__global__ __launch_bounds__(256) void k_transpose_v(const ushort_t* __restrict__ vd,
                                                     ushort_t* __restrict__ vt) {
    __shared__ __attribute__((aligned(16))) ushort_t tile[64 * 72];  // col ^= ((t>>3)&7)<<3
    int bid = blockIdx.x;            // 64 bh x 32 ttiles
    int bh = bid >> 5, tt = bid & 31;
    const ushort_t* src = vd + ((size_t)bh * 2048 + tt * 64) * 64;
    ushort_t* dst = vt + (size_t)bh * 2048 * 64 + tt * 64;
#pragma unroll
    for (int r = 0; r < 2; ++r) {
        int i = r * 256 + threadIdx.x;
        int t = i >> 3, c8 = (i & 7) * 8;
        us8 v = *reinterpret_cast<const us8*>(src + (size_t)t * 64 + c8);
        *reinterpret_cast<us8*>(&tile[t * 72 + (c8 ^ ((t >> 3) << 3))]) = v;
    }
    __syncthreads();
#pragma unroll
    for (int r = 0; r < 2; ++r) {
        int i = r * 256 + threadIdx.x;
        int dh = i >> 3, t8 = (i & 7) * 8;
        us8 o;
#pragma unroll
        for (int e = 0; e < 8; ++e)
            o[e] = tile[(t8 + e) * 72 + (dh ^ ((t8 >> 3) << 3))];
        *reinterpret_cast<us8*>(dst + (size_t)dh * 2048 + t8) = o;
    }
}

// ---------------------------------------------------------------- attention
// 512 blocks = 64 bh (low bits -> XCD affinity) x 8 q-tiles (big-first).
// Block = 4 waves x 64 q-rows = 256-row q-tile. Each wave owns TWO 32-row q-halves,
// so every K/V LDS fragment is reused 2x (halves the LDS-pipe load per MFMA).
// Swapped QK^T in exp2 domain, no max tracking; ctx^T = V^T x P^T; row-sums via
// ones-MFMA. 64-key tiles, dbuf LDS (32 KiB), global_load_lds w16 with
// pre-swizzled source and WAVE-UNIFORM LDS dest (rule #21: HW = base + lane*16).
__global__ __launch_bounds__(256, 2) void k_attn(
    const ushort_t* __restrict__ q, const ushort_t* __restrict__ k,
    const ushort_t* __restrict__ v, ushort_t* __restrict__ ctx) {
    __shared__ __attribute__((aligned(16))) ushort_t lsK[2 * 4096];  // 2 bufs x [64 key][64 dh]
    __shared__ __attribute__((aligned(16))) ushort_t lsV[2 * 4096];  // 2 bufs x [64 dh][64 key]

    const int tid = threadIdx.x, wid = tid >> 6, lane = tid & 63;
    const int l31 = lane & 31, hi = lane >> 5;
    const int bid = blockIdx.x;
    const int bh = bid & 63, qt = 7 - (bid >> 6);   // big q-tiles dispatched first
    const size_t base = (size_t)bh * 2048 * 64;
    const ushort_t* qg = q + base;
    const ushort_t* kg = k + base;
    const ushort_t* vtg = v + base;                 // [dh][t]
    const int b = bh >> 4, h = bh & 15;

    const int q0 = qt * 256;
    const int q0w = q0 + wid * 64;
    const int njt = 4 * qt + 4;                     // 64-key tiles staged by block
    const int ntw = (q0w >> 6) + 1;                 // tiles this wave computes

    // staging: 256 threads x (2 K + 2 V) loads cover 64 rows x 8 chunks of 16B
    const int srow = tid >> 3;                      // = wid*8 + (lane>>3)
    const int ssw = ((((tid & 7) * 16) ^ ((srow & 7) << 4)) >> 1);   // swizzled src chunk (ushorts)
    const ushort_t* kst = kg + (size_t)srow * 64 + ssw;
    const ushort_t* vst = vtg + (size_t)srow * 2048 + ssw;

    const int kx = (l31 & 7) << 4;
    int koffA[4];
#pragma unroll
    for (int s = 0; s < 4; ++s)
        koffA[s] = l31 * 128 + ((s * 32 + hi * 16) ^ kx);

    us8 ow;
#pragma unroll
    for (int e = 0; e < 8; ++e) ow[e] = 0x3F80;     // bf16 1.0
    const bf16x8 onef = __builtin_bit_cast(bf16x8, ow);

    // Q fragments for both q-halves (pre-scaled by 0.125*log2e)
    bf16x8 qf[2][4];
#pragma unroll
    for (int qh = 0; qh < 2; ++qh)
#pragma unroll
        for (int s = 0; s < 4; ++s)
            qf[qh][s] = *reinterpret_cast<const bf16x8*>(
                qg + (size_t)(q0w + qh * 32 + l31) * 64 + s * 16 + hi * 8);

    f32x16 acc00 = {}, acc01 = {}, acc10 = {}, acc11 = {}, lac0 = {}, lac1 = {};

// LDS dest: wave-uniform base (wid*1024); HW fills lane l at base + l*16, which
// lands row srow, chunk (tid&7) -- exactly matching the pre-swizzled source.
#define STAGE(bufb) {                                                                   \
    __builtin_amdgcn_global_load_lds((const AS1 void*)kst,                              \
        (AS3 void*)((AS3 char*)lsK + (bufb) + wid * 1024), 16, 0, 0);                   \
    __builtin_amdgcn_global_load_lds((const AS1 void*)(kst + 2048),                     \
        (AS3 void*)((AS3 char*)lsK + (bufb) + 4096 + wid * 1024), 16, 0, 0);            \
    __builtin_amdgcn_global_load_lds((const AS1 void*)vst,                              \
        (AS3 void*)((AS3 char*)lsV + (bufb) + wid * 1024), 16, 0, 0);                   \
    __builtin_amdgcn_global_load_lds((const AS1 void*)(vst + 65536),                    \
        (AS3 void*)((AS3 char*)lsV + (bufb) + 4096 + wid * 1024), 16, 0, 0);            \
    kst += 4096; vst += 64; }

    STAGE(0);                                       // tile 0 -> buf 0

#pragma unroll 1
    for (int t = 0; t < njt; ++t) {
        __syncthreads();                            // tile t resident (drains vmcnt)
        const int bufc = (t & 1) * 8192;
        if (t + 1 < njt) STAGE(((t + 1) & 1) * 8192);

        if (t < ntw) {
            const char* bK = reinterpret_cast<const char*>(lsK) + bufc;
            const char* bV = reinterpret_cast<const char*>(lsV) + bufc;
            const int j0 = t << 6;
            const int rowA = q0w + l31, rowB = q0w + 32 + l31;

#pragma unroll
            for (int kh = 0; kh < 2; ++kh) {
                // ---- S^T = K x Q for both q-halves (K frags shared)
                f32x16 sA = {}, sB = {};
                __builtin_amdgcn_s_setprio(1);
#pragma unroll
                for (int s = 0; s < 4; ++s) {
                    bf16x8 kf = *reinterpret_cast<const bf16x8*>(bK + kh * 4096 + koffA[s]);
                    sA = __builtin_amdgcn_mfma_f32_32x32x16_bf16(kf, qf[0][s], sA, 0, 0, 0);
                    sB = __builtin_amdgcn_mfma_f32_32x32x16_bf16(kf, qf[1][s], sB, 0, 0, 0);
                }
                __builtin_amdgcn_s_setprio(0);

                // ---- P = exp2(S) with causal zeroing
                const int jh = j0 + kh * 32;
                const bool nmA = (jh + 31 > q0w);
                const bool nmB = (jh + 31 > q0w + 32);
                float pA[16], pB[16];
#pragma unroll
                for (int r = 0; r < 16; ++r) {
                    const int kl = jh + (r & 3) + 8 * (r >> 2) + 4 * hi;
                    float eA = fast_exp2(sA[r]);
                    float eB = fast_exp2(sB[r]);
                    pA[r] = (nmA && kl > rowA) ? 0.f : eA;
                    pB[r] = (nmB && kl > rowB) ? 0.f : eB;
                }

                // ---- pack P -> bf16 frags (both q-halves)
                unsigned pwA[8], pwB[8];
#pragma unroll
                for (int g = 0; g < 4; ++g) {
                    pwA[2 * g]     = cvtpk_bf16(pA[4 * g],     pA[4 * g + 1]);
                    pwA[2 * g + 1] = cvtpk_bf16(pA[4 * g + 2], pA[4 * g + 3]);
                    pwB[2 * g]     = cvtpk_bf16(pB[4 * g],     pB[4 * g + 1]);
                    pwB[2 * g + 1] = cvtpk_bf16(pB[4 * g + 2], pB[4 * g + 3]);
                }
                __builtin_amdgcn_s_setprio(1);
#pragma unroll
                for (int j2 = 0; j2 < 2; ++j2) {
                    asm("v_permlane32_swap_b32 %0, %1" : "+v"(pwA[4 * j2]),     "+v"(pwA[4 * j2 + 2]));
                    asm("v_permlane32_swap_b32 %0, %1" : "+v"(pwA[4 * j2 + 1]), "+v"(pwA[4 * j2 + 3]));
                    asm("v_permlane32_swap_b32 %0, %1" : "+v"(pwB[4 * j2]),     "+v"(pwB[4 * j2 + 2]));
                    asm("v_permlane32_swap_b32 %0, %1" : "+v"(pwB[4 * j2 + 1]), "+v"(pwB[4 * j2 + 3]));
                    u32x4 fwA = { pwA[4 * j2], pwA[4 * j2 + 1], pwA[4 * j2 + 2], pwA[4 * j2 + 3] };
                    u32x4 fwB = { pwB[4 * j2], pwB[4 * j2 + 1], pwB[4 * j2 + 2], pwB[4 * j2 + 3] };
                    bf16x8 pfA = __builtin_bit_cast(bf16x8, fwA);
                    bf16x8 pfB = __builtin_bit_cast(bf16x8, fwB);
                    const int jj = kh * 2 + j2;
                    // ---- PV: V frags shared across q-halves
                    {
                        bf16x8 vf = *reinterpret_cast<const bf16x8*>(bV + koffA[jj]);
                        acc00 = __builtin_amdgcn_mfma_f32_32x32x16_bf16(vf, pfA, acc00, 0, 0, 0);
                        acc10 = __builtin_amdgcn_mfma_f32_32x32x16_bf16(vf, pfB, acc10, 0, 0, 0);
                    }
                    {
                        bf16x8 vf = *reinterpret_cast<const bf16x8*>(bV + 4096 + koffA[jj]);
                        acc01 = __builtin_amdgcn_mfma_f32_32x32x16_bf16(vf, pfA, acc01, 0, 0, 0);
                        acc11 = __builtin_amdgcn_mfma_f32_32x32x16_bf16(vf, pfB, acc11, 0, 0, 0);
                    }
                    lac0 = __builtin_amdgcn_mfma_f32_32x32x16_bf16(onef, pfA, lac0, 0, 0, 0);
                    lac1 = __builtin_amdgcn_mfma_f32_32x32x16_bf16(onef, pfB, lac1, 0, 0, 0);
                }
                __builtin_amdgcn_s_setprio(0);
            }
        }
    }
#undef STAGE

    // ---- epilogue: ctx[b][t][h*64 + dh], dh = dv*32 + 8g + 4hi + e
    {
        float invA = 1.0f / lac0[0];
        float invB = 1.0f / lac1[0];
        size_t orowA = ((size_t)(b * 2048 + q0w + l31)) * 1024 + h * 64;
        size_t orowB = ((size_t)(b * 2048 + q0w + 32 + l31)) * 1024 + h * 64;
#pragma unroll
        for (int g = 0; g < 4; ++g) {
            us4 oA0 = { f2bf(acc00[4 * g] * invA),     f2bf(acc00[4 * g + 1] * invA),
                        f2bf(acc00[4 * g + 2] * invA), f2bf(acc00[4 * g + 3] * invA) };
            *reinterpret_cast<us4*>(&ctx[orowA + 8 * g + 4 * hi]) = oA0;
            us4 oA1 = { f2bf(acc01[4 * g] * invA),     f2bf(acc01[4 * g + 1] * invA),
                        f2bf(acc01[4 * g + 2] * invA), f2bf(acc01[4 * g + 3] * invA) };
            *reinterpret_cast<us4*>(&ctx[orowA + 32 + 8 * g + 4 * hi]) = oA1;
            us4 oB0 = { f2bf(acc10[4 * g] * invB),     f2bf(acc10[4 * g + 1] * invB),
                        f2bf(acc10[4 * g + 2] * invB), f2bf(acc10[4 * g + 3] * invB) };
            *reinterpret_cast<us4*>(&ctx[orowB + 8 * g + 4 * hi]) = oB0;
            us4 oB1 = { f2bf(acc11[4 * g] * invB),     f2bf(acc11[4 * g + 1] * invB),
                        f2bf(acc11[4 * g + 2] * invB), f2bf(acc11[4 * g + 3] * invB) };
            *reinterpret_cast<us4*>(&ctx[orowB + 32 + 8 * g + 4 * hi]) = oB1;
        }
    }
}

// ---------------------------------------------------------------- out GEMM (+bias, f32 out)
// 128x128 tile, BK=64, 4 waves (2x2), 4-phase pipelined schedule, dbuf 64 KiB,
// counted vmcnt, 0-conflict swizzled LDS, XCD swizzle on 512 blocks.
__global__ __launch_bounds__(256, 2) void k_gemm_out(
    const ushort_t* __restrict__ cb, const ushort_t* __restrict__ wot,
    const float* __restrict__ bO, float* __restrict__ out) {
    __shared__ __attribute__((aligned(16))) ushort_t lds[2 * 16384];   // 64 KiB

    const int tid = threadIdx.x, wid = tid >> 6, lane = tid & 63;
    const int lr = lane & 15, lg = lane >> 4;
    const int wm = wid >> 1, wn = wid & 1;

    int bid = blockIdx.x;                       // 512 = 64 per XCD
    int wg = (bid & 7) * 64 + (bid >> 3);       // bijective XCD swizzle
    const int by = wg >> 3, bx = wg & 7;
    const int row0 = by * 128, col0 = bx * 128;

    const int srcrow = lane >> 2;
    const int srccol = (((lane & 3) * 16) ^ ((lane >> 5) << 5)) >> 1;   // ushort units
    const ushort_t* aS = cb  + (size_t)(row0 + srcrow) * 1024 + srccol;
    const ushort_t* bS = wot + (size_t)(col0 + srcrow) * 1024 + srccol;
    const int rdoff = (lr * 64 + lg * 16) ^ ((lr >> 3) << 5);           // bytes

#define STG_A(kt, sr, sc) \
    __builtin_amdgcn_global_load_lds((const AS1 void*)(aS + (size_t)(sr) * 16384 + (kt) * 64 + (sc) * 32), \
        (AS3 void*)((AS3 char*)lds + ((kt) & 1) * 32768 + (sr) * 2048 + (sc) * 1024), 16, 0, 0)
#define STG_B(kt, sr, sc) \
    __builtin_amdgcn_global_load_lds((const AS1 void*)(bS + (size_t)(sr) * 16384 + (kt) * 64 + (sc) * 32), \
        (AS3 void*)((AS3 char*)lds + ((kt) & 1) * 32768 + 16384 + (sr) * 2048 + (sc) * 1024), 16, 0, 0)
#define GRP1(kt)  { STG_A(kt, wid, 0); STG_A(kt, wid + 4, 0); STG_B(kt, wid, 0); STG_B(kt, wid + 4, 0); }
#define GTOP(kt)  { STG_A(kt, wid, 1); STG_A(kt, wid + 4, 1); STG_B(kt, wid, 1); STG_B(kt, wid + 4, 1); }

    f32x4 acc[4][4] = {};

    GRP1(0); GTOP(0); GRP1(1);

#pragma unroll 1
    for (int kt = 0; kt < 16; ++kt) {
        if (kt < 15) asm volatile("s_waitcnt vmcnt(4)" ::: "memory");
        else         asm volatile("s_waitcnt vmcnt(0)" ::: "memory");
        __builtin_amdgcn_s_barrier();
        if (kt < 15) GTOP(kt + 1);

        const char* bufA = (const char*)lds + (kt & 1) * 32768;
        const char* bufB = bufA + 16384;

        bf16x8 av0[2], av1[2], bv0[4], bv1[4];
#pragma unroll
        for (int x = 0; x < 2; ++x)
            av0[x] = *reinterpret_cast<const bf16x8*>(bufA + (wm * 4 + x) * 2048 + rdoff);
#pragma unroll
        for (int x = 0; x < 4; ++x)
            bv0[x] = *reinterpret_cast<const bf16x8*>(bufB + (wn * 4 + x) * 2048 + rdoff);

        // ---- phase 0
#pragma unroll
        for (int x = 0; x < 2; ++x)
            av1[x] = *reinterpret_cast<const bf16x8*>(bufA + (wm * 4 + 2 + x) * 2048 + rdoff);
        __builtin_amdgcn_s_setprio(1);
#pragma unroll
        for (int mf = 0; mf < 2; ++mf)
#pragma unroll
            for (int nf = 0; nf < 4; ++nf)
                acc[mf][nf] = __builtin_amdgcn_mfma_f32_16x16x32_bf16(av0[mf], bv0[nf], acc[mf][nf], 0, 0, 0);
        __builtin_amdgcn_s_setprio(0);
        __builtin_amdgcn_s_barrier();

        // ---- phase 1
#pragma unroll
        for (int x = 0; x < 2; ++x)
            av0[x] = *reinterpret_cast<const bf16x8*>(bufA + (wm * 4 + x) * 2048 + 1024 + rdoff);
#pragma unroll
        for (int x = 0; x < 4; ++x)
            bv1[x] = *reinterpret_cast<const bf16x8*>(bufB + (wn * 4 + x) * 2048 + 1024 + rdoff);
        __builtin_amdgcn_s_setprio(1);
#pragma unroll
        for (int mf = 0; mf < 2; ++mf)
#pragma unroll
            for (int nf = 0; nf < 4; ++nf)
                acc[2 + mf][nf] = __builtin_amdgcn_mfma_f32_16x16x32_bf16(av1[mf], bv0[nf], acc[2 + mf][nf], 0, 0, 0);
        __builtin_amdgcn_s_setprio(0);
        if (kt < 14) GRP1(kt + 2);
        __builtin_amdgcn_s_barrier();

        // ---- phase 2
#pragma unroll
        for (int x = 0; x < 2; ++x)
            av1[x] = *reinterpret_cast<const bf16x8*>(bufA + (wm * 4 + 2 + x) * 2048 + 1024 + rdoff);
        __builtin_amdgcn_s_setprio(1);
#pragma unroll
        for (int mf = 0; mf < 2; ++mf)
#pragma unroll
            for (int nf = 0; nf < 4; ++nf)
                acc[mf][nf] = __builtin_amdgcn_mfma_f32_16x16x32_bf16(av0[mf], bv1[nf], acc[mf][nf], 0, 0, 0);
        __builtin_amdgcn_s_setprio(0);
        __builtin_amdgcn_s_barrier();

        // ---- phase 3
        __builtin_amdgcn_s_setprio(1);
#pragma unroll
        for (int mf = 0; mf < 2; ++mf)
#pragma unroll
            for (int nf = 0; nf < 4; ++nf)
                acc[2 + mf][nf] = __builtin_amdgcn_mfma_f32_16x16x32_bf16(av1[mf], bv1[nf], acc[2 + mf][nf], 0, 0, 0);
        __builtin_amdgcn_s_setprio(0);
    }
#undef STG_A
#undef STG_B
#undef GRP1
#undef GTOP

#pragma unroll
    for (int mf = 0; mf < 4; ++mf) {
#pragma unroll
        for (int nf = 0; nf < 4; ++nf) {
            int col = col0 + wn * 64 + nf * 16 + lr;
            float bias = bO[col];
#pragma unroll
            for (int e = 0; e < 4; ++e) {
                int row = row0 + wm * 64 + mf * 16 + lg * 4 + e;
                out[(size_t)row * 1024 + col] = acc[mf][nf][e] + bias;
            }
        }
    }
}

// ---------------------------------------------------------------- launch
extern "C" void kernel_launch(void* const* d_in, const int* in_sizes, int n_in,
                              void* d_out, int out_size, void* d_ws, size_t ws_size,
                              hipStream_t stream) {
    const float* x  = (const float*)d_in[0];
    const float* wq = (const float*)d_in[1];
    const float* wk = (const float*)d_in[2];
    const float* wv = (const float*)d_in[3];
    const float* wo = (const float*)d_in[4];
    const float* bo = (const float*)d_in[5];
    float* out = (float*)d_out;

    char* ws = (char*)d_ws;
    ushort_t* xb    = (ushort_t*)(ws);                 // 16 MB   x bf16 [8192][1024]; reused as V^T after gemm
    ushort_t* wqkvt = (ushort_t*)(ws + 16777216);      // 6 MB    [3][1024 n][1024 k] = [3072][1024]
    ushort_t* wot   = (ushort_t*)(ws + 23068672);      // 2 MB    [1024 n][1024 k]
    ushort_t* qd    = (ushort_t*)(ws + 25165824);      // 16 MB   [B,H,T,Dh] (pre-scaled)
    ushort_t* kd    = (ushort_t*)(ws + 41943040);      // 16 MB   [B,H,T,Dh]
    ushort_t* vd    = (ushort_t*)(ws + 58720256);      // 16 MB   [B,H,T,Dh]
    ushort_t* cd    = (ushort_t*)(ws + 75497472);      // 16 MB   ctx bf16 [8192][1024]
    ushort_t* vt    = xb;                              // V^T [B,H,Dh,T] (xb dead after gemm_qkv)

    k_convert_x<<<2048, 256, 0, stream>>>(x, xb, 8192 * 1024 / 4);
    k_transpose_w<<<1024, 256, 0, stream>>>(wq, wk, wv, wo, wqkvt, wot);
    k_gemm_qkv256<<<512, 512, 0, stream>>>(xb, wqkvt, qd, kd, vd);
    k_transpose_v<<<2048, 256, 0, stream>>>(vd, vt);
    k_attn<<<512, 256, 0, stream>>>(qd, kd, vt, cd);
    k_gemm_out<<<dim3(512), 256, 0, stream>>>(cd, wot, bo, out);
}